// Round 4
// baseline (1073.481 us; speedup 1.0000x reference)
//
#include <hip/hip_runtime.h>
#include <math.h>

typedef unsigned short u16;
typedef __attribute__((ext_vector_type(8))) short bf16x8;
typedef __attribute__((ext_vector_type(4))) float f32x4;
typedef __attribute__((ext_vector_type(4))) unsigned short u16x4;
typedef __attribute__((ext_vector_type(8))) unsigned short u16x8;

constexpr int Sq = 2048, Dm = 1024, Hh = 16, DH = 64;
constexpr int NT = 4096;                 // tokens (B*S)
constexpr float SEXP = 0.125f * 1.44269504f;   // scale * log2(e), folded into Q

__device__ __forceinline__ u16 f2bf(float f) {
    unsigned u = __float_as_uint(f);
    return (u16)((u + 0x7FFF + ((u >> 16) & 1)) >> 16);
}

// async global->LDS, 16B per lane; LDS base is wave-uniform, HW adds lane*16
__device__ __forceinline__ void async16(u16* lds, const u16* g) {
    __builtin_amdgcn_global_load_lds(
        (const __attribute__((address_space(1))) unsigned int*)g,
        (__attribute__((address_space(3))) unsigned int*)lds, 16, 0, 0);
}

__device__ __forceinline__ float lam_of(const int* lidx, const float* lamp) {
    float lf = (float)lidx[0];
    float init = 0.8f - 0.6f * __expf(-0.3f * fmaxf(lf - 1.0f, 0.0f));
    return fminf(fmaxf(init * lamp[0], 0.1f), 0.9f);
}

// ---------------------------------------------------------------------------
// 128x128 MFMA GEMM mainloop.  A:[M][K], Bt:[N][K] bf16.
// ---------------------------------------------------------------------------
__device__ __forceinline__ void gemm_tile_128(
    const u16* __restrict__ A, const u16* __restrict__ Bt, int K,
    int aRow0, int bCol0, u16* As, u16* Bs, f32x4 acc[4][4])
{
    const int tid = threadIdx.x;
    const int w = tid >> 6, lane = tid & 63;
    const int ln = lane & 15, quad = lane >> 4;
    const int wm = (w >> 1) * 64, wn = (w & 1) * 64;
    const int l3 = lane & 7, lr8 = lane >> 3;

    for (int kt = 0; kt < K; kt += 64) {
        __syncthreads();
        #pragma unroll
        for (int c0 = 0; c0 < 4; ++c0) {
            int c = w * 4 + c0;
            int lr = c * 8 + lr8;
            int sc = l3 ^ (lr & 7);
            async16(As + c * 512, A + (size_t)(aRow0 + lr) * K + kt + sc * 8);
            async16(Bs + c * 512, Bt + (size_t)(bCol0 + lr) * K + kt + sc * 8);
        }
        __syncthreads();
        #pragma unroll
        for (int kc = 0; kc < 2; ++kc) {
            bf16x8 af[4], bfr[4];
            #pragma unroll
            for (int mt = 0; mt < 4; ++mt)
                af[mt] = *(const bf16x8*)(As + (wm + mt * 16 + ln) * 64 +
                                          (((kc * 4 + quad) ^ (ln & 7)) * 8));
            #pragma unroll
            for (int nt = 0; nt < 4; ++nt)
                bfr[nt] = *(const bf16x8*)(Bs + (wn + nt * 16 + ln) * 64 +
                                           (((kc * 4 + quad) ^ (ln & 7)) * 8));
            #pragma unroll
            for (int mt = 0; mt < 4; ++mt)
                #pragma unroll
                for (int nt = 0; nt < 4; ++nt)
                    acc[mt][nt] = __builtin_amdgcn_mfma_f32_16x16x32_bf16(
                        af[mt], bfr[nt], acc[mt][nt], 0, 0, 0);
        }
    }
}

// ---------------------------------------------------------------------------
// 64x128 MFMA GEMM mainloop (combine/final)
// ---------------------------------------------------------------------------
__device__ __forceinline__ void gemm_tile_64(
    const u16* __restrict__ A, const u16* __restrict__ Bt, int K,
    int aRow0, int bCol0, u16* As, u16* Bs, f32x4 acc[2][4])
{
    const int tid = threadIdx.x;
    const int w = tid >> 6, lane = tid & 63;
    const int ln = lane & 15, quad = lane >> 4;
    const int wm = (w >> 1) * 32, wn = (w & 1) * 64;
    const int l3 = lane & 7, lr8 = lane >> 3;

    for (int kt = 0; kt < K; kt += 64) {
        __syncthreads();
        #pragma unroll
        for (int c0 = 0; c0 < 2; ++c0) {
            int c = w * 2 + c0;
            int lr = c * 8 + lr8;
            int sc = l3 ^ (lr & 7);
            async16(As + c * 512, A + (size_t)(aRow0 + lr) * K + kt + sc * 8);
        }
        #pragma unroll
        for (int c0 = 0; c0 < 4; ++c0) {
            int c = w * 4 + c0;
            int lr = c * 8 + lr8;
            int sc = l3 ^ (lr & 7);
            async16(Bs + c * 512, Bt + (size_t)(bCol0 + lr) * K + kt + sc * 8);
        }
        __syncthreads();
        #pragma unroll
        for (int kc = 0; kc < 2; ++kc) {
            bf16x8 af[2], bfr[4];
            #pragma unroll
            for (int mt = 0; mt < 2; ++mt)
                af[mt] = *(const bf16x8*)(As + (wm + mt * 16 + ln) * 64 +
                                          (((kc * 4 + quad) ^ (ln & 7)) * 8));
            #pragma unroll
            for (int nt = 0; nt < 4; ++nt)
                bfr[nt] = *(const bf16x8*)(Bs + (wn + nt * 16 + ln) * 64 +
                                           (((kc * 4 + quad) ^ (ln & 7)) * 8));
            #pragma unroll
            for (int mt = 0; mt < 2; ++mt)
                #pragma unroll
                for (int nt = 0; nt < 4; ++nt)
                    acc[mt][nt] = __builtin_amdgcn_mfma_f32_16x16x32_bf16(
                        af[mt], bfr[nt], acc[mt][nt], 0, 0, 0);
        }
    }
}

// ---------------------------------------------------------------------------
__global__ __launch_bounds__(256)
void convert_x(const float* __restrict__ x, u16* __restrict__ xb)
{
    int i = (blockIdx.x * 256 + threadIdx.x) * 4;
    float4 v = *(const float4*)(x + i);
    u16x4 o;
    o.x = f2bf(v.x); o.y = f2bf(v.y); o.z = f2bf(v.z); o.w = f2bf(v.w);
    *(u16x4*)(xb + i) = o;
}

// ---------------------------------------------------------------------------
// Weight transpose-convert
// ---------------------------------------------------------------------------
struct TcP { const float* src[9]; u16* dst[9]; int ld[9]; int coff[9]; };

__global__ __launch_bounds__(256)
void wconv(TcP p, const int* __restrict__ lidx, const float* __restrict__ lamp)
{
    __shared__ float t[64][65];
    const int z = blockIdx.z;
    const float scale = (z == 7) ? -lam_of(lidx, lamp) : 1.0f;
    const float* __restrict__ src = p.src[z];
    u16* __restrict__ dst = p.dst[z];
    const int kb = blockIdx.y * 64, nb = blockIdx.x * 64;
    const int tid = threadIdx.x;
    {
        int r = tid >> 2, cs = (tid & 3) * 16;
        #pragma unroll
        for (int j4 = 0; j4 < 16; j4 += 4) {
            float4 v = *(const float4*)&src[(size_t)(kb + r) * 1024 + nb + cs + j4];
            t[r][cs + j4 + 0] = v.x; t[r][cs + j4 + 1] = v.y;
            t[r][cs + j4 + 2] = v.z; t[r][cs + j4 + 3] = v.w;
        }
    }
    __syncthreads();
    {
        int n = tid >> 2, ks = (tid & 3) * 16;
        u16x8 a, b;
        #pragma unroll
        for (int j = 0; j < 8; ++j) a[j] = f2bf(scale * t[ks + j][n]);
        #pragma unroll
        for (int j = 0; j < 8; ++j) b[j] = f2bf(scale * t[ks + 8 + j][n]);
        u16* o = &dst[(size_t)(nb + n) * p.ld[z] + p.coff[z] + kb + ks];
        *(u16x8*)o = a;
        *(u16x8*)(o + 8) = b;
    }
}

// ---------------------------------------------------------------------------
// QKV projection.  Q -> [bh][s][64] PRE-SCALED by SEXP.  K,V -> frag order.
// ---------------------------------------------------------------------------
struct QkvP { const u16* Wt[6]; const float* bias[6]; u16* out[6]; };

__global__ __launch_bounds__(256, 3)
void qkv_mfma(const u16* __restrict__ xb, QkvP p)
{
    __shared__ u16 As[128 * 64], Bs[128 * 64];
    const int z = blockIdx.z;
    const int type = (z < 3) ? z : z - 3;   // 0=q 1=k 2=v
    const int aRow0 = blockIdx.y * 128, nCol0 = blockIdx.x * 128;
    f32x4 acc[4][4] = {};
    gemm_tile_128(xb, p.Wt[z], 1024, aRow0, nCol0, As, Bs, acc);

    const float* __restrict__ bias = p.bias[z];
    u16* __restrict__ out = p.out[z];
    const int tid = threadIdx.x, w = tid >> 6, lane = tid & 63;
    const int ln = lane & 15, quad = lane >> 4;
    const int wm = (w >> 1) * 64, wn = (w & 1) * 64;
    #pragma unroll
    for (int mt = 0; mt < 4; ++mt) {
        #pragma unroll
        for (int nt = 0; nt < 4; ++nt) {
            int gn = nCol0 + wn + nt * 16 + ln;
            int h = gn >> 6, dh = gn & 63;
            float bv = bias[gn];
            #pragma unroll
            for (int r = 0; r < 4; ++r) {
                int gm = aRow0 + wm + mt * 16 + quad * 4 + r;
                int b = gm >> 11, s = gm & (Sq - 1);
                size_t bh = (size_t)(b * Hh + h);
                float fv = acc[mt][nt][r] + bv;
                size_t idx;
                u16 val;
                if (type == 0) {
                    val = f2bf(fv * SEXP);           // fold softmax scale
                    idx = bh * 131072 + (size_t)s * 64 + dh;
                } else if (type == 1) {
                    val = f2bf(fv);
                    idx = bh * 131072 + (size_t)(s >> 5) * 2048 +
                          (size_t)((dh >> 5) * 2 + ((s >> 4) & 1)) * 512 +
                          (size_t)(((dh >> 3) & 3) * 16 + (s & 15)) * 8 + (dh & 7);
                } else {
                    val = f2bf(fv);
                    int kidx = ((s & 15) * 2) + ((s >> 4) & 1);
                    idx = bh * 131072 + (size_t)(s >> 5) * 2048 +
                          (size_t)(dh >> 4) * 512 +
                          (size_t)((kidx >> 3) * 16 + (dh & 15)) * 8 + (kidx & 7);
                }
                out[idx] = val;
            }
        }
    }
}

// ---------------------------------------------------------------------------
// Flash attention, barrier-free main loop; atomic-LDS wave merge (20.5 KB).
// Grid: (bh, qblk, br) so all q-blocks of one bh share an XCD (id%8=bh%8).
// ---------------------------------------------------------------------------
__global__ __launch_bounds__(256, 4)
void attn_mfma(const u16* __restrict__ q1, const u16* __restrict__ kf1,
               const u16* __restrict__ vf1,
               const u16* __restrict__ q2, const u16* __restrict__ kf2,
               const u16* __restrict__ vf2, u16* __restrict__ ocat)
{
    // P regions 4 x 5120 B; after main loop reused as merge: [64][68] f32 + l
    __shared__ __align__(16) char smem[20480];

    const int bh = blockIdx.x, qblk = blockIdx.y, br = blockIdx.z;
    const u16* __restrict__ q  = br ? q2  : q1;
    const u16* __restrict__ kf = br ? kf2 : kf1;
    const u16* __restrict__ vf = br ? vf2 : vf1;

    const int tid = threadIdx.x, w = tid >> 6, lane = tid & 63;
    const int ln = lane & 15, quad = lane >> 4;
    char* Pbase = smem + w * 5120;

    // hoist Q A-frags (A[m=q][k=d]; lane: m=ln, k=quad*8+j)
    const u16* qbase = q + (size_t)bh * 131072 + (size_t)(qblk * 64) * 64;
    bf16x8 qf[4][2];
    #pragma unroll
    for (int mt = 0; mt < 4; ++mt)
        #pragma unroll
        for (int kc = 0; kc < 2; ++kc)
            qf[mt][kc] = *(const bf16x8*)(qbase + (mt * 16 + ln) * 64 +
                                          kc * 32 + quad * 8);

    bf16x8 ones;
    #pragma unroll
    for (int j = 0; j < 8; ++j) ones[j] = (short)0x3F80;

    f32x4 oacc[4][4] = {};
    f32x4 lacc[4] = {};

    const u16* kbase = kf + (size_t)bh * 131072 + lane * 8;
    const u16* vbase = vf + (size_t)bh * 131072 + lane * 8;

    for (int it = 0; it < 16; ++it) {
        const int kt = it * 4 + w;
        const u16* kp = kbase + (size_t)kt * 2048;
        const u16* vp = vbase + (size_t)kt * 2048;

        bf16x8 kfr[2][2], vfr[4];
        #pragma unroll
        for (int kc = 0; kc < 2; ++kc)
            #pragma unroll
            for (int nt = 0; nt < 2; ++nt)
                kfr[nt][kc] = *(const bf16x8*)(kp + (kc * 2 + nt) * 512);
        #pragma unroll
        for (int dt = 0; dt < 4; ++dt)
            vfr[dt] = *(const bf16x8*)(vp + dt * 512);

        // S = Q K^T (Q pre-scaled)
        f32x4 sacc[4][2] = {};
        #pragma unroll
        for (int kc = 0; kc < 2; ++kc)
            #pragma unroll
            for (int mt = 0; mt < 4; ++mt)
                #pragma unroll
                for (int nt = 0; nt < 2; ++nt)
                    sacc[mt][nt] = __builtin_amdgcn_mfma_f32_16x16x32_bf16(
                        qf[mt][kc], kfr[nt][kc], sacc[mt][nt], 0, 0, 0);

        // no-max softmax: p = 2^s; pack pairs -> dword, round, swizzled write
        #pragma unroll
        for (int mt = 0; mt < 4; ++mt) {
            #pragma unroll
            for (int r = 0; r < 4; ++r) {
                float p0 = exp2f(sacc[mt][0][r]);
                float p1 = exp2f(sacc[mt][1][r]);
                unsigned a  = __float_as_uint(p0) + 0x8000u;
                unsigned b2 = __float_as_uint(p1) + 0x8000u;
                unsigned pk = __builtin_amdgcn_perm(b2, a, 0x07060302);
                int row = mt * 16 + quad * 4 + r;
                *(unsigned*)(Pbase + row * 80 + (((ln >> 2) ^ r) << 4) +
                             ((ln & 3) << 2)) = pk;
            }
        }

        // O += P V ; l += P . 1
        #pragma unroll
        for (int mt = 0; mt < 4; ++mt) {
            bf16x8 pf = *(const bf16x8*)(Pbase + (mt * 16 + ln) * 80 +
                                         ((quad ^ (ln & 3)) << 4));
            lacc[mt] = __builtin_amdgcn_mfma_f32_16x16x32_bf16(
                pf, ones, lacc[mt], 0, 0, 0);
            #pragma unroll
            for (int dt = 0; dt < 4; ++dt)
                oacc[mt][dt] = __builtin_amdgcn_mfma_f32_16x16x32_bf16(
                    pf, vfr[dt], oacc[mt][dt], 0, 0, 0);
        }
    }

    // ---- merge: zero LDS, atomic-add partials, normalize ----
    __syncthreads();                       // all P reads done; LDS reused
    float* mrg  = (float*)smem;            // [64][68]
    float* lmrg = (float*)(smem + 17408);  // [64]
    for (int i = tid; i < 4416; i += 256) ((float*)smem)[i] = 0.0f;
    __syncthreads();
    #pragma unroll
    for (int mt = 0; mt < 4; ++mt) {
        #pragma unroll
        for (int dt = 0; dt < 4; ++dt)
            #pragma unroll
            for (int r = 0; r < 4; ++r)
                atomicAdd(&mrg[(mt * 16 + quad * 4 + r) * 68 + dt * 16 + ln],
                          oacc[mt][dt][r]);
        if (ln == 0)
            #pragma unroll
            for (int r = 0; r < 4; ++r)
                atomicAdd(&lmrg[mt * 16 + quad * 4 + r], lacc[mt][r]);
    }
    __syncthreads();

    {
        int qr = tid >> 2, dg = tid & 3;
        float inv = 1.0f / lmrg[qr];
        float vals[16];
        #pragma unroll
        for (int c = 0; c < 4; ++c) {
            f32x4 v0 = *(f32x4*)(mrg + qr * 68 + dg * 16 + c * 4);
            #pragma unroll
            for (int i = 0; i < 4; ++i) vals[c * 4 + i] = v0[i] * inv;
        }
        int token = (bh >> 4) * 2048 + qblk * 64 + qr;
        size_t base = (size_t)token * 2048 + br * 1024 + (bh & 15) * 64 + dg * 16;
        u16x8 o0, o1;
        #pragma unroll
        for (int i = 0; i < 8; ++i) { o0[i] = f2bf(vals[i]); o1[i] = f2bf(vals[8 + i]); }
        *(u16x8*)(ocat + base) = o0;
        *(u16x8*)(ocat + base + 8) = o1;
    }
}

// ---------------------------------------------------------------------------
// Combine: adiff = ocat[4096][2048] @ Wcmb^T + (bo1 - lam*bo2)  -> bf16
// ---------------------------------------------------------------------------
__global__ __launch_bounds__(256, 4)
void combine_mfma(const u16* __restrict__ ocat, const u16* __restrict__ Wcmb,
                  const float* __restrict__ bo1, const float* __restrict__ bo2,
                  const int* __restrict__ lidx, const float* __restrict__ lamp,
                  u16* __restrict__ adiff)
{
    __shared__ u16 As[64 * 64], Bs[128 * 64];
    const int aRow0 = blockIdx.y * 64, nCol0 = blockIdx.x * 128;
    f32x4 acc[2][4] = {};
    gemm_tile_64(ocat, Wcmb, 2048, aRow0, nCol0, As, Bs, acc);

    const float lam = lam_of(lidx, lamp);
    const int tid = threadIdx.x, w = tid >> 6, lane = tid & 63;
    const int ln = lane & 15, quad = lane >> 4;
    const int wm = (w >> 1) * 32, wn = (w & 1) * 64;
    #pragma unroll
    for (int mt = 0; mt < 2; ++mt) {
        #pragma unroll
        for (int nt = 0; nt < 4; ++nt) {
            int gn = nCol0 + wn + nt * 16 + ln;
            float bv = bo1[gn] - lam * bo2[gn];
            #pragma unroll
            for (int r = 0; r < 4; ++r) {
                int gm = aRow0 + wm + mt * 16 + quad * 4 + r;
                adiff[(size_t)gm * 1024 + gn] = f2bf(acc[mt][nt][r] + bv);
            }
        }
    }
}

// ---------------------------------------------------------------------------
// Final: out = adiff @ Wp^T + bp   (fp32 out)
// ---------------------------------------------------------------------------
__global__ __launch_bounds__(256, 4)
void final_mfma(const u16* __restrict__ adiff, const u16* __restrict__ Wpt,
                const float* __restrict__ bp, float* __restrict__ outb)
{
    __shared__ u16 As[64 * 64], Bs[128 * 64];
    const int aRow0 = blockIdx.y * 64, nCol0 = blockIdx.x * 128;
    f32x4 acc[2][4] = {};
    gemm_tile_64(adiff, Wpt, 1024, aRow0, nCol0, As, Bs, acc);

    const int tid = threadIdx.x, w = tid >> 6, lane = tid & 63;
    const int ln = lane & 15, quad = lane >> 4;
    const int wm = (w >> 1) * 32, wn = (w & 1) * 64;
    #pragma unroll
    for (int mt = 0; mt < 2; ++mt) {
        #pragma unroll
        for (int nt = 0; nt < 4; ++nt) {
            int gn = nCol0 + wn + nt * 16 + ln;
            float bv = bp[gn];
            #pragma unroll
            for (int r = 0; r < 4; ++r) {
                int gm = aRow0 + wm + mt * 16 + quad * 4 + r;
                outb[(size_t)gm * 1024 + gn] = acc[mt][nt][r] + bv;
            }
        }
    }
}

// ---------------------------------------------------------------------------
extern "C" void kernel_launch(void* const* d_in, const int* in_sizes, int n_in,
                              void* d_out, int out_size, void* d_ws, size_t ws_size,
                              hipStream_t stream)
{
    const float* x    = (const float*)d_in[0];
    const int*   lidx = (const int*)  d_in[1];
    const float* lamp = (const float*)d_in[2];
    const float* Wq1  = (const float*)d_in[3];
    const float* Wk1  = (const float*)d_in[4];
    const float* Wv1  = (const float*)d_in[5];
    const float* Wo1  = (const float*)d_in[6];
    const float* bq1  = (const float*)d_in[7];
    const float* bk1  = (const float*)d_in[8];
    const float* bv1  = (const float*)d_in[9];
    const float* bo1  = (const float*)d_in[10];
    const float* Wq2  = (const float*)d_in[11];
    const float* Wk2  = (const float*)d_in[12];
    const float* Wv2  = (const float*)d_in[13];
    const float* Wo2  = (const float*)d_in[14];
    const float* bq2  = (const float*)d_in[15];
    const float* bk2  = (const float*)d_in[16];
    const float* bv2  = (const float*)d_in[17];
    const float* bo2  = (const float*)d_in[18];
    const float* Wp   = (const float*)d_in[19];
    const float* bp   = (const float*)d_in[20];

    char* wsb = (char*)d_ws;
    const size_t MB = 1 << 20;
    u16* xb   = (u16*)(wsb + 0 * MB);          // 8 MB
    u16* Wt0  = (u16*)(wsb + 8 * MB);          // 6 x 2 MB
    u16* Wcmb = (u16*)(wsb + 20 * MB);         // 4 MB
    u16* Wpt  = (u16*)(wsb + 24 * MB);         // 2 MB
    u16* qb1  = (u16*)(wsb + 26 * MB);         // 8 MB each
    u16* kb1  = (u16*)(wsb + 34 * MB);         // fragged
    u16* vb1  = (u16*)(wsb + 42 * MB);         // fragged
    u16* qb2  = (u16*)(wsb + 50 * MB);
    u16* kb2  = (u16*)(wsb + 58 * MB);
    u16* vb2  = (u16*)(wsb + 66 * MB);
    u16* ocat = (u16*)(wsb + 74 * MB);         // 16 MB
    u16* adif = (u16*)(wsb + 90 * MB);         // 8 MB

    convert_x<<<dim3(NT * Dm / 1024), dim3(256), 0, stream>>>(x, xb);

    TcP tp;
    const float* wsrc[9] = {Wq1, Wk1, Wv1, Wq2, Wk2, Wv2, Wo1, Wo2, Wp};
    for (int i = 0; i < 9; ++i) tp.src[i] = wsrc[i];
    for (int i = 0; i < 6; ++i) { tp.dst[i] = Wt0 + (size_t)i * 1024 * 1024; tp.ld[i] = 1024; tp.coff[i] = 0; }
    tp.dst[6] = Wcmb; tp.ld[6] = 2048; tp.coff[6] = 0;
    tp.dst[7] = Wcmb; tp.ld[7] = 2048; tp.coff[7] = 1024;
    tp.dst[8] = Wpt;  tp.ld[8] = 1024; tp.coff[8] = 0;
    wconv<<<dim3(16, 16, 9), dim3(256), 0, stream>>>(tp, lidx, lamp);

    QkvP qp;
    qp.Wt[0] = Wt0 + 0 * 1048576; qp.bias[0] = bq1; qp.out[0] = qb1;
    qp.Wt[1] = Wt0 + 1 * 1048576; qp.bias[1] = bk1; qp.out[1] = kb1;
    qp.Wt[2] = Wt0 + 2 * 1048576; qp.bias[2] = bv1; qp.out[2] = vb1;
    qp.Wt[3] = Wt0 + 3 * 1048576; qp.bias[3] = bq2; qp.out[3] = qb2;
    qp.Wt[4] = Wt0 + 4 * 1048576; qp.bias[4] = bk2; qp.out[4] = kb2;
    qp.Wt[5] = Wt0 + 5 * 1048576; qp.bias[5] = bv2; qp.out[5] = vb2;
    qkv_mfma<<<dim3(8, 32, 6), dim3(256), 0, stream>>>(xb, qp);

    attn_mfma<<<dim3(32, 32, 2), dim3(256), 0, stream>>>(
        qb1, kb1, vb1, qb2, kb2, vb2, ocat);

    combine_mfma<<<dim3(8, 64), dim3(256), 0, stream>>>(
        ocat, Wcmb, bo1, bo2, lidx, lamp, adif);

    final_mfma<<<dim3(8, 64), dim3(256), 0, stream>>>(
        adif, Wpt, bp, (float*)d_out);
}

// Round 5
// 352.780 us; speedup vs baseline: 3.0429x; 3.0429x over previous
//
#include <hip/hip_runtime.h>
#include <math.h>

typedef unsigned short u16;
typedef __attribute__((ext_vector_type(8))) short bf16x8;
typedef __attribute__((ext_vector_type(4))) float f32x4;
typedef __attribute__((ext_vector_type(4))) unsigned short u16x4;
typedef __attribute__((ext_vector_type(8))) unsigned short u16x8;

constexpr int Sq = 2048, Dm = 1024, Hh = 16, DH = 64;
constexpr int NT = 4096;                 // tokens (B*S)
constexpr float SEXP = 0.125f * 1.44269504f;   // scale * log2(e), folded into Q

__device__ __forceinline__ u16 f2bf(float f) {
    unsigned u = __float_as_uint(f);
    return (u16)((u + 0x7FFF + ((u >> 16) & 1)) >> 16);
}

// async global->LDS, 16B per lane; LDS base is wave-uniform, HW adds lane*16
__device__ __forceinline__ void async16(u16* lds, const u16* g) {
    __builtin_amdgcn_global_load_lds(
        (const __attribute__((address_space(1))) unsigned int*)g,
        (__attribute__((address_space(3))) unsigned int*)lds, 16, 0, 0);
}

__device__ __forceinline__ float lam_of(const int* lidx, const float* lamp) {
    float lf = (float)lidx[0];
    float init = 0.8f - 0.6f * __expf(-0.3f * fmaxf(lf - 1.0f, 0.0f));
    return fminf(fmaxf(init * lamp[0], 0.1f), 0.9f);
}

// ---------------------------------------------------------------------------
// 128x128 MFMA GEMM mainloop.  A:[M][K], Bt:[N][K] bf16.
// ---------------------------------------------------------------------------
__device__ __forceinline__ void gemm_tile_128(
    const u16* __restrict__ A, const u16* __restrict__ Bt, int K,
    int aRow0, int bCol0, u16* As, u16* Bs, f32x4 acc[4][4])
{
    const int tid = threadIdx.x;
    const int w = tid >> 6, lane = tid & 63;
    const int ln = lane & 15, quad = lane >> 4;
    const int wm = (w >> 1) * 64, wn = (w & 1) * 64;
    const int l3 = lane & 7, lr8 = lane >> 3;

    for (int kt = 0; kt < K; kt += 64) {
        __syncthreads();
        #pragma unroll
        for (int c0 = 0; c0 < 4; ++c0) {
            int c = w * 4 + c0;
            int lr = c * 8 + lr8;
            int sc = l3 ^ (lr & 7);
            async16(As + c * 512, A + (size_t)(aRow0 + lr) * K + kt + sc * 8);
            async16(Bs + c * 512, Bt + (size_t)(bCol0 + lr) * K + kt + sc * 8);
        }
        __syncthreads();
        #pragma unroll
        for (int kc = 0; kc < 2; ++kc) {
            bf16x8 af[4], bfr[4];
            #pragma unroll
            for (int mt = 0; mt < 4; ++mt)
                af[mt] = *(const bf16x8*)(As + (wm + mt * 16 + ln) * 64 +
                                          (((kc * 4 + quad) ^ (ln & 7)) * 8));
            #pragma unroll
            for (int nt = 0; nt < 4; ++nt)
                bfr[nt] = *(const bf16x8*)(Bs + (wn + nt * 16 + ln) * 64 +
                                           (((kc * 4 + quad) ^ (ln & 7)) * 8));
            #pragma unroll
            for (int mt = 0; mt < 4; ++mt)
                #pragma unroll
                for (int nt = 0; nt < 4; ++nt)
                    acc[mt][nt] = __builtin_amdgcn_mfma_f32_16x16x32_bf16(
                        af[mt], bfr[nt], acc[mt][nt], 0, 0, 0);
        }
    }
}

// ---------------------------------------------------------------------------
// 64x128 MFMA GEMM mainloop (combine/final)
// ---------------------------------------------------------------------------
__device__ __forceinline__ void gemm_tile_64(
    const u16* __restrict__ A, const u16* __restrict__ Bt, int K,
    int aRow0, int bCol0, u16* As, u16* Bs, f32x4 acc[2][4])
{
    const int tid = threadIdx.x;
    const int w = tid >> 6, lane = tid & 63;
    const int ln = lane & 15, quad = lane >> 4;
    const int wm = (w >> 1) * 32, wn = (w & 1) * 64;
    const int l3 = lane & 7, lr8 = lane >> 3;

    for (int kt = 0; kt < K; kt += 64) {
        __syncthreads();
        #pragma unroll
        for (int c0 = 0; c0 < 2; ++c0) {
            int c = w * 2 + c0;
            int lr = c * 8 + lr8;
            int sc = l3 ^ (lr & 7);
            async16(As + c * 512, A + (size_t)(aRow0 + lr) * K + kt + sc * 8);
        }
        #pragma unroll
        for (int c0 = 0; c0 < 4; ++c0) {
            int c = w * 4 + c0;
            int lr = c * 8 + lr8;
            int sc = l3 ^ (lr & 7);
            async16(Bs + c * 512, Bt + (size_t)(bCol0 + lr) * K + kt + sc * 8);
        }
        __syncthreads();
        #pragma unroll
        for (int kc = 0; kc < 2; ++kc) {
            bf16x8 af[2], bfr[4];
            #pragma unroll
            for (int mt = 0; mt < 2; ++mt)
                af[mt] = *(const bf16x8*)(As + (wm + mt * 16 + ln) * 64 +
                                          (((kc * 4 + quad) ^ (ln & 7)) * 8));
            #pragma unroll
            for (int nt = 0; nt < 4; ++nt)
                bfr[nt] = *(const bf16x8*)(Bs + (wn + nt * 16 + ln) * 64 +
                                           (((kc * 4 + quad) ^ (ln & 7)) * 8));
            #pragma unroll
            for (int mt = 0; mt < 2; ++mt)
                #pragma unroll
                for (int nt = 0; nt < 4; ++nt)
                    acc[mt][nt] = __builtin_amdgcn_mfma_f32_16x16x32_bf16(
                        af[mt], bfr[nt], acc[mt][nt], 0, 0, 0);
        }
    }
}

// ---------------------------------------------------------------------------
__global__ __launch_bounds__(256)
void convert_x(const float* __restrict__ x, u16* __restrict__ xb)
{
    int i = (blockIdx.x * 256 + threadIdx.x) * 4;
    float4 v = *(const float4*)(x + i);
    u16x4 o;
    o.x = f2bf(v.x); o.y = f2bf(v.y); o.z = f2bf(v.z); o.w = f2bf(v.w);
    *(u16x4*)(xb + i) = o;
}

// ---------------------------------------------------------------------------
// Weight transpose-convert
// ---------------------------------------------------------------------------
struct TcP { const float* src[9]; u16* dst[9]; int ld[9]; int coff[9]; };

__global__ __launch_bounds__(256)
void wconv(TcP p, const int* __restrict__ lidx, const float* __restrict__ lamp)
{
    __shared__ float t[64][65];
    const int z = blockIdx.z;
    const float scale = (z == 7) ? -lam_of(lidx, lamp) : 1.0f;
    const float* __restrict__ src = p.src[z];
    u16* __restrict__ dst = p.dst[z];
    const int kb = blockIdx.y * 64, nb = blockIdx.x * 64;
    const int tid = threadIdx.x;
    {
        int r = tid >> 2, cs = (tid & 3) * 16;
        #pragma unroll
        for (int j4 = 0; j4 < 16; j4 += 4) {
            float4 v = *(const float4*)&src[(size_t)(kb + r) * 1024 + nb + cs + j4];
            t[r][cs + j4 + 0] = v.x; t[r][cs + j4 + 1] = v.y;
            t[r][cs + j4 + 2] = v.z; t[r][cs + j4 + 3] = v.w;
        }
    }
    __syncthreads();
    {
        int n = tid >> 2, ks = (tid & 3) * 16;
        u16x8 a, b;
        #pragma unroll
        for (int j = 0; j < 8; ++j) a[j] = f2bf(scale * t[ks + j][n]);
        #pragma unroll
        for (int j = 0; j < 8; ++j) b[j] = f2bf(scale * t[ks + 8 + j][n]);
        u16* o = &dst[(size_t)(nb + n) * p.ld[z] + p.coff[z] + kb + ks];
        *(u16x8*)o = a;
        *(u16x8*)(o + 8) = b;
    }
}

// ---------------------------------------------------------------------------
// QKV projection.  Q -> [bh][s][64] PRE-SCALED by SEXP.  K,V -> frag order.
// ---------------------------------------------------------------------------
struct QkvP { const u16* Wt[6]; const float* bias[6]; u16* out[6]; };

__global__ __launch_bounds__(256, 3)
void qkv_mfma(const u16* __restrict__ xb, QkvP p)
{
    __shared__ u16 As[128 * 64], Bs[128 * 64];
    const int z = blockIdx.z;
    const int type = (z < 3) ? z : z - 3;   // 0=q 1=k 2=v
    const int aRow0 = blockIdx.y * 128, nCol0 = blockIdx.x * 128;
    f32x4 acc[4][4] = {};
    gemm_tile_128(xb, p.Wt[z], 1024, aRow0, nCol0, As, Bs, acc);

    const float* __restrict__ bias = p.bias[z];
    u16* __restrict__ out = p.out[z];
    const int tid = threadIdx.x, w = tid >> 6, lane = tid & 63;
    const int ln = lane & 15, quad = lane >> 4;
    const int wm = (w >> 1) * 64, wn = (w & 1) * 64;
    #pragma unroll
    for (int mt = 0; mt < 4; ++mt) {
        #pragma unroll
        for (int nt = 0; nt < 4; ++nt) {
            int gn = nCol0 + wn + nt * 16 + ln;
            int h = gn >> 6, dh = gn & 63;
            float bv = bias[gn];
            #pragma unroll
            for (int r = 0; r < 4; ++r) {
                int gm = aRow0 + wm + mt * 16 + quad * 4 + r;
                int b = gm >> 11, s = gm & (Sq - 1);
                size_t bh = (size_t)(b * Hh + h);
                float fv = acc[mt][nt][r] + bv;
                size_t idx;
                u16 val;
                if (type == 0) {
                    val = f2bf(fv * SEXP);           // fold softmax scale
                    idx = bh * 131072 + (size_t)s * 64 + dh;
                } else if (type == 1) {
                    val = f2bf(fv);
                    idx = bh * 131072 + (size_t)(s >> 5) * 2048 +
                          (size_t)((dh >> 5) * 2 + ((s >> 4) & 1)) * 512 +
                          (size_t)(((dh >> 3) & 3) * 16 + (s & 15)) * 8 + (dh & 7);
                } else {
                    val = f2bf(fv);
                    int kidx = ((s & 15) * 2) + ((s >> 4) & 1);
                    idx = bh * 131072 + (size_t)(s >> 5) * 2048 +
                          (size_t)(dh >> 4) * 512 +
                          (size_t)((kidx >> 3) * 16 + (dh & 15)) * 8 + (kidx & 7);
                }
                out[idx] = val;
            }
        }
    }
}

// ---------------------------------------------------------------------------
// Flash attention, no barriers/merge.  Block = 128 q-rows; wave w owns rows
// [w*32, w*32+32) x ALL 2048 keys.  All 4 waves sweep the same key tile ->
// identical frag loads hit L1; raw s_barrier keeps them lockstep (no memory
// semantics -> no vmcnt drain).  Regs ~120 -> true 4 waves/SIMD.
// ---------------------------------------------------------------------------
__global__ __launch_bounds__(256, 4)
void attn_mfma(const u16* __restrict__ q1, const u16* __restrict__ kf1,
               const u16* __restrict__ vf1,
               const u16* __restrict__ q2, const u16* __restrict__ kf2,
               const u16* __restrict__ vf2, u16* __restrict__ ocat)
{
    __shared__ __align__(16) char smem[10240];   // 4 x 2560 B per-wave P

    const int bh = blockIdx.x, qblk = blockIdx.y, br = blockIdx.z;
    const u16* __restrict__ q  = br ? q2  : q1;
    const u16* __restrict__ kf = br ? kf2 : kf1;
    const u16* __restrict__ vf = br ? vf2 : vf1;

    const int tid = threadIdx.x, w = tid >> 6, lane = tid & 63;
    const int ln = lane & 15, quad = lane >> 4;
    char* Pbase = smem + w * 2560;

    // Q A-frags for this wave's 32 rows (A[m=q][k=d]; lane: m=ln, k=quad*8+j)
    const u16* qbase = q + (size_t)bh * 131072 +
                       (size_t)(qblk * 128 + w * 32) * 64;
    bf16x8 qf[2][2];
    #pragma unroll
    for (int mt = 0; mt < 2; ++mt)
        #pragma unroll
        for (int kc = 0; kc < 2; ++kc)
            qf[mt][kc] = *(const bf16x8*)(qbase + (mt * 16 + ln) * 64 +
                                          kc * 32 + quad * 8);

    bf16x8 ones;
    #pragma unroll
    for (int j = 0; j < 8; ++j) ones[j] = (short)0x3F80;

    f32x4 oacc[2][4] = {};
    f32x4 lacc[2] = {};

    const u16* kbase = kf + (size_t)bh * 131072 + lane * 8;
    const u16* vbase = vf + (size_t)bh * 131072 + lane * 8;

    for (int kt = 0; kt < 64; ++kt) {
        const u16* kp = kbase + (size_t)kt * 2048;
        const u16* vp = vbase + (size_t)kt * 2048;

        bf16x8 kfr[2][2];
        #pragma unroll
        for (int kc = 0; kc < 2; ++kc)
            #pragma unroll
            for (int nt = 0; nt < 2; ++nt)
                kfr[nt][kc] = *(const bf16x8*)(kp + (kc * 2 + nt) * 512);

        // S = Q K^T (Q pre-scaled by SEXP)
        f32x4 sacc[2][2] = {};
        #pragma unroll
        for (int kc = 0; kc < 2; ++kc)
            #pragma unroll
            for (int mt = 0; mt < 2; ++mt)
                #pragma unroll
                for (int nt = 0; nt < 2; ++nt)
                    sacc[mt][nt] = __builtin_amdgcn_mfma_f32_16x16x32_bf16(
                        qf[mt][kc], kfr[nt][kc], sacc[mt][nt], 0, 0, 0);

        // p = 2^s; pack key-pairs (k_idx = 2*ln + nt) -> dword, swizzled write
        #pragma unroll
        for (int mt = 0; mt < 2; ++mt) {
            #pragma unroll
            for (int r = 0; r < 4; ++r) {
                float p0 = exp2f(sacc[mt][0][r]);
                float p1 = exp2f(sacc[mt][1][r]);
                unsigned a  = __float_as_uint(p0) + 0x8000u;
                unsigned b2 = __float_as_uint(p1) + 0x8000u;
                unsigned pk = __builtin_amdgcn_perm(b2, a, 0x07060302);
                int row = mt * 16 + quad * 4 + r;
                *(unsigned*)(Pbase + row * 80 + (((ln >> 2) ^ r) << 4) +
                             ((ln & 3) << 2)) = pk;
            }
        }

        // V frags loaded after sacc dies (shorter live range)
        bf16x8 vfr[4];
        #pragma unroll
        for (int dt = 0; dt < 4; ++dt)
            vfr[dt] = *(const bf16x8*)(vp + dt * 512);

        // O += P V ; l += P . 1
        #pragma unroll
        for (int mt = 0; mt < 2; ++mt) {
            bf16x8 pf = *(const bf16x8*)(Pbase + (mt * 16 + ln) * 80 +
                                         ((quad ^ (ln & 3)) << 4));
            lacc[mt] = __builtin_amdgcn_mfma_f32_16x16x32_bf16(
                pf, ones, lacc[mt], 0, 0, 0);
            #pragma unroll
            for (int dt = 0; dt < 4; ++dt)
                oacc[mt][dt] = __builtin_amdgcn_mfma_f32_16x16x32_bf16(
                    pf, vfr[dt], oacc[mt][dt], 0, 0, 0);
        }

        __builtin_amdgcn_s_barrier();   // lockstep only (no memory fence)
    }

    // epilogue: wave-complete rows -> normalize and store
    const int b = bh >> 4, h = bh & 15;
    #pragma unroll
    for (int mt = 0; mt < 2; ++mt) {
        #pragma unroll
        for (int r = 0; r < 4; ++r) {
            float inv = 1.0f / lacc[mt][r];
            int s = qblk * 128 + w * 32 + mt * 16 + quad * 4 + r;
            size_t rowb = (size_t)(b * Sq + s) * 2048 + br * 1024 + h * 64;
            #pragma unroll
            for (int dt = 0; dt < 4; ++dt)
                ocat[rowb + dt * 16 + ln] = f2bf(oacc[mt][dt][r] * inv);
        }
    }
}

// ---------------------------------------------------------------------------
// Combine: adiff = ocat[4096][2048] @ Wcmb^T + (bo1 - lam*bo2)  -> bf16
// ---------------------------------------------------------------------------
__global__ __launch_bounds__(256, 4)
void combine_mfma(const u16* __restrict__ ocat, const u16* __restrict__ Wcmb,
                  const float* __restrict__ bo1, const float* __restrict__ bo2,
                  const int* __restrict__ lidx, const float* __restrict__ lamp,
                  u16* __restrict__ adiff)
{
    __shared__ u16 As[64 * 64], Bs[128 * 64];
    const int aRow0 = blockIdx.y * 64, nCol0 = blockIdx.x * 128;
    f32x4 acc[2][4] = {};
    gemm_tile_64(ocat, Wcmb, 2048, aRow0, nCol0, As, Bs, acc);

    const float lam = lam_of(lidx, lamp);
    const int tid = threadIdx.x, w = tid >> 6, lane = tid & 63;
    const int ln = lane & 15, quad = lane >> 4;
    const int wm = (w >> 1) * 32, wn = (w & 1) * 64;
    #pragma unroll
    for (int mt = 0; mt < 2; ++mt) {
        #pragma unroll
        for (int nt = 0; nt < 4; ++nt) {
            int gn = nCol0 + wn + nt * 16 + ln;
            float bv = bo1[gn] - lam * bo2[gn];
            #pragma unroll
            for (int r = 0; r < 4; ++r) {
                int gm = aRow0 + wm + mt * 16 + quad * 4 + r;
                adiff[(size_t)gm * 1024 + gn] = f2bf(acc[mt][nt][r] + bv);
            }
        }
    }
}

// ---------------------------------------------------------------------------
// Final: out = adiff @ Wp^T + bp   (fp32 out)
// ---------------------------------------------------------------------------
__global__ __launch_bounds__(256, 4)
void final_mfma(const u16* __restrict__ adiff, const u16* __restrict__ Wpt,
                const float* __restrict__ bp, float* __restrict__ outb)
{
    __shared__ u16 As[64 * 64], Bs[128 * 64];
    const int aRow0 = blockIdx.y * 64, nCol0 = blockIdx.x * 128;
    f32x4 acc[2][4] = {};
    gemm_tile_64(adiff, Wpt, 1024, aRow0, nCol0, As, Bs, acc);

    const int tid = threadIdx.x, w = tid >> 6, lane = tid & 63;
    const int ln = lane & 15, quad = lane >> 4;
    const int wm = (w >> 1) * 32, wn = (w & 1) * 64;
    #pragma unroll
    for (int mt = 0; mt < 2; ++mt) {
        #pragma unroll
        for (int nt = 0; nt < 4; ++nt) {
            int gn = nCol0 + wn + nt * 16 + ln;
            float bv = bp[gn];
            #pragma unroll
            for (int r = 0; r < 4; ++r) {
                int gm = aRow0 + wm + mt * 16 + quad * 4 + r;
                outb[(size_t)gm * 1024 + gn] = acc[mt][nt][r] + bv;
            }
        }
    }
}

// ---------------------------------------------------------------------------
extern "C" void kernel_launch(void* const* d_in, const int* in_sizes, int n_in,
                              void* d_out, int out_size, void* d_ws, size_t ws_size,
                              hipStream_t stream)
{
    const float* x    = (const float*)d_in[0];
    const int*   lidx = (const int*)  d_in[1];
    const float* lamp = (const float*)d_in[2];
    const float* Wq1  = (const float*)d_in[3];
    const float* Wk1  = (const float*)d_in[4];
    const float* Wv1  = (const float*)d_in[5];
    const float* Wo1  = (const float*)d_in[6];
    const float* bq1  = (const float*)d_in[7];
    const float* bk1  = (const float*)d_in[8];
    const float* bv1  = (const float*)d_in[9];
    const float* bo1  = (const float*)d_in[10];
    const float* Wq2  = (const float*)d_in[11];
    const float* Wk2  = (const float*)d_in[12];
    const float* Wv2  = (const float*)d_in[13];
    const float* Wo2  = (const float*)d_in[14];
    const float* bq2  = (const float*)d_in[15];
    const float* bk2  = (const float*)d_in[16];
    const float* bv2  = (const float*)d_in[17];
    const float* bo2  = (const float*)d_in[18];
    const float* Wp   = (const float*)d_in[19];
    const float* bp   = (const float*)d_in[20];

    char* wsb = (char*)d_ws;
    const size_t MB = 1 << 20;
    u16* xb   = (u16*)(wsb + 0 * MB);          // 8 MB
    u16* Wt0  = (u16*)(wsb + 8 * MB);          // 6 x 2 MB
    u16* Wcmb = (u16*)(wsb + 20 * MB);         // 4 MB
    u16* Wpt  = (u16*)(wsb + 24 * MB);         // 2 MB
    u16* qb1  = (u16*)(wsb + 26 * MB);         // 8 MB each
    u16* kb1  = (u16*)(wsb + 34 * MB);         // fragged
    u16* vb1  = (u16*)(wsb + 42 * MB);         // fragged
    u16* qb2  = (u16*)(wsb + 50 * MB);
    u16* kb2  = (u16*)(wsb + 58 * MB);
    u16* vb2  = (u16*)(wsb + 66 * MB);
    u16* ocat = (u16*)(wsb + 74 * MB);         // 16 MB
    u16* adif = (u16*)(wsb + 90 * MB);         // 8 MB

    convert_x<<<dim3(NT * Dm / 1024), dim3(256), 0, stream>>>(x, xb);

    TcP tp;
    const float* wsrc[9] = {Wq1, Wk1, Wv1, Wq2, Wk2, Wv2, Wo1, Wo2, Wp};
    for (int i = 0; i < 9; ++i) tp.src[i] = wsrc[i];
    for (int i = 0; i < 6; ++i) { tp.dst[i] = Wt0 + (size_t)i * 1024 * 1024; tp.ld[i] = 1024; tp.coff[i] = 0; }
    tp.dst[6] = Wcmb; tp.ld[6] = 2048; tp.coff[6] = 0;
    tp.dst[7] = Wcmb; tp.ld[7] = 2048; tp.coff[7] = 1024;
    tp.dst[8] = Wpt;  tp.ld[8] = 1024; tp.coff[8] = 0;
    wconv<<<dim3(16, 16, 9), dim3(256), 0, stream>>>(tp, lidx, lamp);

    QkvP qp;
    qp.Wt[0] = Wt0 + 0 * 1048576; qp.bias[0] = bq1; qp.out[0] = qb1;
    qp.Wt[1] = Wt0 + 1 * 1048576; qp.bias[1] = bk1; qp.out[1] = kb1;
    qp.Wt[2] = Wt0 + 2 * 1048576; qp.bias[2] = bv1; qp.out[2] = vb1;
    qp.Wt[3] = Wt0 + 3 * 1048576; qp.bias[3] = bq2; qp.out[3] = qb2;
    qp.Wt[4] = Wt0 + 4 * 1048576; qp.bias[4] = bk2; qp.out[4] = kb2;
    qp.Wt[5] = Wt0 + 5 * 1048576; qp.bias[5] = bv2; qp.out[5] = vb2;
    qkv_mfma<<<dim3(8, 32, 6), dim3(256), 0, stream>>>(xb, qp);

    attn_mfma<<<dim3(32, 16, 2), dim3(256), 0, stream>>>(
        qb1, kb1, vb1, qb2, kb2, vb2, ocat);

    combine_mfma<<<dim3(8, 64), dim3(256), 0, stream>>>(
        ocat, Wcmb, bo1, bo2, lidx, lamp, adif);

    final_mfma<<<dim3(8, 64), dim3(256), 0, stream>>>(
        adif, Wpt, bp, (float*)d_out);
}

// Round 6
// 333.197 us; speedup vs baseline: 3.2218x; 1.0588x over previous
//
#include <hip/hip_runtime.h>
#include <math.h>

typedef unsigned short u16;
typedef __attribute__((ext_vector_type(8))) short bf16x8;
typedef __attribute__((ext_vector_type(4))) float f32x4;
typedef __attribute__((ext_vector_type(4))) unsigned short u16x4;
typedef __attribute__((ext_vector_type(8))) unsigned short u16x8;

constexpr int Sq = 2048, Dm = 1024, Hh = 16, DH = 64;
constexpr int NT = 4096;                 // tokens (B*S)
constexpr float SEXP = 0.125f * 1.44269504f;   // scale * log2(e), folded into Q

#if __has_builtin(__builtin_amdgcn_exp2f)
#define EXP2(x) __builtin_amdgcn_exp2f(x)
#else
#define EXP2(x) exp2f(x)
#endif

__device__ __forceinline__ u16 f2bf(float f) {
    unsigned u = __float_as_uint(f);
    return (u16)((u + 0x7FFF + ((u >> 16) & 1)) >> 16);
}

// async global->LDS, 16B per lane; LDS base is wave-uniform, HW adds lane*16
__device__ __forceinline__ void async16(u16* lds, const u16* g) {
    __builtin_amdgcn_global_load_lds(
        (const __attribute__((address_space(1))) unsigned int*)g,
        (__attribute__((address_space(3))) unsigned int*)lds, 16, 0, 0);
}

__device__ __forceinline__ float lam_of(const int* lidx, const float* lamp) {
    float lf = (float)lidx[0];
    float init = 0.8f - 0.6f * __expf(-0.3f * fmaxf(lf - 1.0f, 0.0f));
    return fminf(fmaxf(init * lamp[0], 0.1f), 0.9f);
}

// ---------------------------------------------------------------------------
// 128x128 MFMA GEMM mainloop.  A:[M][K], Bt:[N][K] bf16.
// ---------------------------------------------------------------------------
__device__ __forceinline__ void gemm_tile_128(
    const u16* __restrict__ A, const u16* __restrict__ Bt, int K,
    int aRow0, int bCol0, u16* As, u16* Bs, f32x4 acc[4][4])
{
    const int tid = threadIdx.x;
    const int w = tid >> 6, lane = tid & 63;
    const int ln = lane & 15, quad = lane >> 4;
    const int wm = (w >> 1) * 64, wn = (w & 1) * 64;
    const int l3 = lane & 7, lr8 = lane >> 3;

    for (int kt = 0; kt < K; kt += 64) {
        __syncthreads();
        #pragma unroll
        for (int c0 = 0; c0 < 4; ++c0) {
            int c = w * 4 + c0;
            int lr = c * 8 + lr8;
            int sc = l3 ^ (lr & 7);
            async16(As + c * 512, A + (size_t)(aRow0 + lr) * K + kt + sc * 8);
            async16(Bs + c * 512, Bt + (size_t)(bCol0 + lr) * K + kt + sc * 8);
        }
        __syncthreads();
        #pragma unroll
        for (int kc = 0; kc < 2; ++kc) {
            bf16x8 af[4], bfr[4];
            #pragma unroll
            for (int mt = 0; mt < 4; ++mt)
                af[mt] = *(const bf16x8*)(As + (wm + mt * 16 + ln) * 64 +
                                          (((kc * 4 + quad) ^ (ln & 7)) * 8));
            #pragma unroll
            for (int nt = 0; nt < 4; ++nt)
                bfr[nt] = *(const bf16x8*)(Bs + (wn + nt * 16 + ln) * 64 +
                                           (((kc * 4 + quad) ^ (ln & 7)) * 8));
            #pragma unroll
            for (int mt = 0; mt < 4; ++mt)
                #pragma unroll
                for (int nt = 0; nt < 4; ++nt)
                    acc[mt][nt] = __builtin_amdgcn_mfma_f32_16x16x32_bf16(
                        af[mt], bfr[nt], acc[mt][nt], 0, 0, 0);
        }
    }
}

// ---------------------------------------------------------------------------
// 64x128 MFMA GEMM mainloop
// ---------------------------------------------------------------------------
__device__ __forceinline__ void gemm_tile_64(
    const u16* __restrict__ A, const u16* __restrict__ Bt, int K,
    int aRow0, int bCol0, u16* As, u16* Bs, f32x4 acc[2][4])
{
    const int tid = threadIdx.x;
    const int w = tid >> 6, lane = tid & 63;
    const int ln = lane & 15, quad = lane >> 4;
    const int wm = (w >> 1) * 32, wn = (w & 1) * 64;
    const int l3 = lane & 7, lr8 = lane >> 3;

    for (int kt = 0; kt < K; kt += 64) {
        __syncthreads();
        #pragma unroll
        for (int c0 = 0; c0 < 2; ++c0) {
            int c = w * 2 + c0;
            int lr = c * 8 + lr8;
            int sc = l3 ^ (lr & 7);
            async16(As + c * 512, A + (size_t)(aRow0 + lr) * K + kt + sc * 8);
        }
        #pragma unroll
        for (int c0 = 0; c0 < 4; ++c0) {
            int c = w * 4 + c0;
            int lr = c * 8 + lr8;
            int sc = l3 ^ (lr & 7);
            async16(Bs + c * 512, Bt + (size_t)(bCol0 + lr) * K + kt + sc * 8);
        }
        __syncthreads();
        #pragma unroll
        for (int kc = 0; kc < 2; ++kc) {
            bf16x8 af[2], bfr[4];
            #pragma unroll
            for (int mt = 0; mt < 2; ++mt)
                af[mt] = *(const bf16x8*)(As + (wm + mt * 16 + ln) * 64 +
                                          (((kc * 4 + quad) ^ (ln & 7)) * 8));
            #pragma unroll
            for (int nt = 0; nt < 4; ++nt)
                bfr[nt] = *(const bf16x8*)(Bs + (wn + nt * 16 + ln) * 64 +
                                           (((kc * 4 + quad) ^ (ln & 7)) * 8));
            #pragma unroll
            for (int mt = 0; mt < 2; ++mt)
                #pragma unroll
                for (int nt = 0; nt < 4; ++nt)
                    acc[mt][nt] = __builtin_amdgcn_mfma_f32_16x16x32_bf16(
                        af[mt], bfr[nt], acc[mt][nt], 0, 0, 0);
        }
    }
}

// ---------------------------------------------------------------------------
__global__ __launch_bounds__(256)
void convert_x(const float* __restrict__ x, u16* __restrict__ xb)
{
    int i = (blockIdx.x * 256 + threadIdx.x) * 4;
    float4 v = *(const float4*)(x + i);
    u16x4 o;
    o.x = f2bf(v.x); o.y = f2bf(v.y); o.z = f2bf(v.z); o.w = f2bf(v.w);
    *(u16x4*)(xb + i) = o;
}

// ---------------------------------------------------------------------------
// Weight transpose-convert: 7 slices (6 QKV weights + Wp -> Wpt)
// ---------------------------------------------------------------------------
struct TcP { const float* src[7]; u16* dst[7]; };

__global__ __launch_bounds__(256)
void wconv(TcP p)
{
    __shared__ float t[64][65];
    const int z = blockIdx.z;
    const float* __restrict__ src = p.src[z];
    u16* __restrict__ dst = p.dst[z];
    const int kb = blockIdx.y * 64, nb = blockIdx.x * 64;
    const int tid = threadIdx.x;
    {
        int r = tid >> 2, cs = (tid & 3) * 16;
        #pragma unroll
        for (int j4 = 0; j4 < 16; j4 += 4) {
            float4 v = *(const float4*)&src[(size_t)(kb + r) * 1024 + nb + cs + j4];
            t[r][cs + j4 + 0] = v.x; t[r][cs + j4 + 1] = v.y;
            t[r][cs + j4 + 2] = v.z; t[r][cs + j4 + 3] = v.w;
        }
    }
    __syncthreads();
    {
        int n = tid >> 2, ks = (tid & 3) * 16;
        u16x8 a, b;
        #pragma unroll
        for (int j = 0; j < 8; ++j) a[j] = f2bf(t[ks + j][n]);
        #pragma unroll
        for (int j = 0; j < 8; ++j) b[j] = f2bf(t[ks + 8 + j][n]);
        u16* o = &dst[(size_t)(nb + n) * 1024 + kb + ks];
        *(u16x8*)o = a;
        *(u16x8*)(o + 8) = b;
    }
}

// ---------------------------------------------------------------------------
// Acat build: rows 0..1023 = bf16(Wo1), rows 1024..2047 = bf16(-lam*Wo2),
// row 2048 = bf16(bo1 - lam*bo2)  (bias folded as extra GEMM row)
// ---------------------------------------------------------------------------
__global__ __launch_bounds__(256)
void woconv(const float* __restrict__ Wo1, const float* __restrict__ Wo2,
            const float* __restrict__ bo1, const float* __restrict__ bo2,
            const int* __restrict__ lidx, const float* __restrict__ lamp,
            u16* __restrict__ Acat)
{
    const float lam = lam_of(lidx, lamp);
    int i = (blockIdx.x * 256 + threadIdx.x) * 4;
    float4 v;
    if (i < 1048576) {
        v = *(const float4*)(Wo1 + i);
    } else if (i < 2097152) {
        v = *(const float4*)(Wo2 + (i - 1048576));
        v.x *= -lam; v.y *= -lam; v.z *= -lam; v.w *= -lam;
    } else {
        int c = i - 2097152;
        float4 a = *(const float4*)(bo1 + c);
        float4 b = *(const float4*)(bo2 + c);
        v.x = a.x - lam * b.x; v.y = a.y - lam * b.y;
        v.z = a.z - lam * b.z; v.w = a.w - lam * b.w;
    }
    u16x4 o;
    o.x = f2bf(v.x); o.y = f2bf(v.y); o.z = f2bf(v.z); o.w = f2bf(v.w);
    *(u16x4*)(Acat + i) = o;
}

// ---------------------------------------------------------------------------
// Wfull GEMM: C[m=k][n] = Acat[2112x1024] @ Wpt^T ; store transposed ->
// Wfull_bt[n][m] bf16 for m<2048; row m==2048 -> bfull[n] = acc + bp[n] (f32)
// ---------------------------------------------------------------------------
__global__ __launch_bounds__(256, 4)
void wfull_mfma(const u16* __restrict__ Acat, const u16* __restrict__ Wpt,
                const float* __restrict__ bp, u16* __restrict__ Wfull_bt,
                float* __restrict__ bfull)
{
    __shared__ u16 As[64 * 64], Bs[128 * 64];
    const int aRow0 = blockIdx.y * 64, nCol0 = blockIdx.x * 128;
    f32x4 acc[2][4] = {};
    gemm_tile_64(Acat, Wpt, 1024, aRow0, nCol0, As, Bs, acc);

    const int tid = threadIdx.x, w = tid >> 6, lane = tid & 63;
    const int ln = lane & 15, quad = lane >> 4;
    const int wm = (w >> 1) * 32, wn = (w & 1) * 64;
    #pragma unroll
    for (int mt = 0; mt < 2; ++mt) {
        #pragma unroll
        for (int nt = 0; nt < 4; ++nt) {
            int gn = nCol0 + wn + nt * 16 + ln;
            #pragma unroll
            for (int r = 0; r < 4; ++r) {
                int gm = aRow0 + wm + mt * 16 + quad * 4 + r;
                if (gm < 2048)
                    Wfull_bt[(size_t)gn * 2048 + gm] = f2bf(acc[mt][nt][r]);
                else if (gm == 2048)
                    bfull[gn] = acc[mt][nt][r] + bp[gn];
            }
        }
    }
}

// ---------------------------------------------------------------------------
// QKV projection.  Q -> [bh][s][64] PRE-SCALED by SEXP.  K,V -> frag order.
// ---------------------------------------------------------------------------
struct QkvP { const u16* Wt[6]; const float* bias[6]; u16* out[6]; };

__global__ __launch_bounds__(256, 3)
void qkv_mfma(const u16* __restrict__ xb, QkvP p)
{
    __shared__ u16 As[128 * 64], Bs[128 * 64];
    const int z = blockIdx.z;
    const int type = (z < 3) ? z : z - 3;   // 0=q 1=k 2=v
    const int aRow0 = blockIdx.y * 128, nCol0 = blockIdx.x * 128;
    f32x4 acc[4][4] = {};
    gemm_tile_128(xb, p.Wt[z], 1024, aRow0, nCol0, As, Bs, acc);

    const float* __restrict__ bias = p.bias[z];
    u16* __restrict__ out = p.out[z];
    const int tid = threadIdx.x, w = tid >> 6, lane = tid & 63;
    const int ln = lane & 15, quad = lane >> 4;
    const int wm = (w >> 1) * 64, wn = (w & 1) * 64;
    #pragma unroll
    for (int mt = 0; mt < 4; ++mt) {
        #pragma unroll
        for (int nt = 0; nt < 4; ++nt) {
            int gn = nCol0 + wn + nt * 16 + ln;
            int h = gn >> 6, dh = gn & 63;
            float bv = bias[gn];
            #pragma unroll
            for (int r = 0; r < 4; ++r) {
                int gm = aRow0 + wm + mt * 16 + quad * 4 + r;
                int b = gm >> 11, s = gm & (Sq - 1);
                size_t bh = (size_t)(b * Hh + h);
                float fv = acc[mt][nt][r] + bv;
                size_t idx;
                u16 val;
                if (type == 0) {
                    val = f2bf(fv * SEXP);           // fold softmax scale
                    idx = bh * 131072 + (size_t)s * 64 + dh;
                } else if (type == 1) {
                    val = f2bf(fv);
                    idx = bh * 131072 + (size_t)(s >> 5) * 2048 +
                          (size_t)((dh >> 5) * 2 + ((s >> 4) & 1)) * 512 +
                          (size_t)(((dh >> 3) & 3) * 16 + (s & 15)) * 8 + (dh & 7);
                } else {
                    val = f2bf(fv);
                    int kidx = ((s & 15) * 2) + ((s >> 4) & 1);
                    idx = bh * 131072 + (size_t)(s >> 5) * 2048 +
                          (size_t)(dh >> 4) * 512 +
                          (size_t)((kidx >> 3) * 16 + (dh & 15)) * 8 + (kidx & 7);
                }
                out[idx] = val;
            }
        }
    }
}

// ---------------------------------------------------------------------------
// Flash attention.  Wave = 32 q-rows x all 2048 keys; direct fragged K/V
// loads (L1-shared across the 4 lockstep waves); no-max softmax; P via
// per-wave LDS; raw s_barrier every 2 key-tiles.
// ---------------------------------------------------------------------------
__global__ __launch_bounds__(256, 4)
void attn_mfma(const u16* __restrict__ q1, const u16* __restrict__ kf1,
               const u16* __restrict__ vf1,
               const u16* __restrict__ q2, const u16* __restrict__ kf2,
               const u16* __restrict__ vf2, u16* __restrict__ ocat)
{
    __shared__ __align__(16) char smem[10240];   // 4 x 2560 B per-wave P

    const int bh = blockIdx.x, qblk = blockIdx.y, br = blockIdx.z;
    const u16* __restrict__ q  = br ? q2  : q1;
    const u16* __restrict__ kf = br ? kf2 : kf1;
    const u16* __restrict__ vf = br ? vf2 : vf1;

    const int tid = threadIdx.x, w = tid >> 6, lane = tid & 63;
    const int ln = lane & 15, quad = lane >> 4;
    char* Pbase = smem + w * 2560;

    const u16* qbase = q + (size_t)bh * 131072 +
                       (size_t)(qblk * 128 + w * 32) * 64;
    bf16x8 qf[2][2];
    #pragma unroll
    for (int mt = 0; mt < 2; ++mt)
        #pragma unroll
        for (int kc = 0; kc < 2; ++kc)
            qf[mt][kc] = *(const bf16x8*)(qbase + (mt * 16 + ln) * 64 +
                                          kc * 32 + quad * 8);

    bf16x8 ones;
    #pragma unroll
    for (int j = 0; j < 8; ++j) ones[j] = (short)0x3F80;
    const f32x4 zero4 = {0.f, 0.f, 0.f, 0.f};

    f32x4 oacc[2][4] = {};
    f32x4 lacc[2] = {};

    const u16* kbase = kf + (size_t)bh * 131072 + lane * 8;
    const u16* vbase = vf + (size_t)bh * 131072 + lane * 8;

    for (int it = 0; it < 32; ++it) {
        #pragma unroll
        for (int u = 0; u < 2; ++u) {
            const int kt = it * 2 + u;
            const u16* kp = kbase + (size_t)kt * 2048;
            const u16* vp = vbase + (size_t)kt * 2048;

            bf16x8 kfr[2][2];
            #pragma unroll
            for (int kc = 0; kc < 2; ++kc)
                #pragma unroll
                for (int nt = 0; nt < 2; ++nt)
                    kfr[nt][kc] = *(const bf16x8*)(kp + (kc * 2 + nt) * 512);

            // S = Q K^T (Q pre-scaled); kc=0 uses zero C (no init movs)
            f32x4 sacc[2][2];
            #pragma unroll
            for (int mt = 0; mt < 2; ++mt)
                #pragma unroll
                for (int nt = 0; nt < 2; ++nt)
                    sacc[mt][nt] = __builtin_amdgcn_mfma_f32_16x16x32_bf16(
                        qf[mt][0], kfr[nt][0], zero4, 0, 0, 0);
            #pragma unroll
            for (int mt = 0; mt < 2; ++mt)
                #pragma unroll
                for (int nt = 0; nt < 2; ++nt)
                    sacc[mt][nt] = __builtin_amdgcn_mfma_f32_16x16x32_bf16(
                        qf[mt][1], kfr[nt][1], sacc[mt][nt], 0, 0, 0);

            // p = 2^s; pack key-pairs (k_idx=2*ln+nt) -> dword, swizzled write
            #pragma unroll
            for (int mt = 0; mt < 2; ++mt) {
                #pragma unroll
                for (int r = 0; r < 4; ++r) {
                    float p0 = EXP2(sacc[mt][0][r]);
                    float p1 = EXP2(sacc[mt][1][r]);
                    unsigned a  = __float_as_uint(p0) + 0x8000u;
                    unsigned b2 = __float_as_uint(p1) + 0x8000u;
                    unsigned pk = __builtin_amdgcn_perm(b2, a, 0x07060302);
                    int row = mt * 16 + quad * 4 + r;
                    *(unsigned*)(Pbase + row * 80 + (((ln >> 2) ^ r) << 4) +
                                 ((ln & 3) << 2)) = pk;
                }
            }

            bf16x8 vfr[4];
            #pragma unroll
            for (int dt = 0; dt < 4; ++dt)
                vfr[dt] = *(const bf16x8*)(vp + dt * 512);

            // O += P V ; l += P . 1
            #pragma unroll
            for (int mt = 0; mt < 2; ++mt) {
                bf16x8 pf = *(const bf16x8*)(Pbase + (mt * 16 + ln) * 80 +
                                             ((quad ^ (ln & 3)) << 4));
                lacc[mt] = __builtin_amdgcn_mfma_f32_16x16x32_bf16(
                    pf, ones, lacc[mt], 0, 0, 0);
                #pragma unroll
                for (int dt = 0; dt < 4; ++dt)
                    oacc[mt][dt] = __builtin_amdgcn_mfma_f32_16x16x32_bf16(
                        pf, vfr[dt], oacc[mt][dt], 0, 0, 0);
            }
        }
        __builtin_amdgcn_s_barrier();   // lockstep only (no memory fence)
    }

    // epilogue: wave-complete rows -> normalize and store
    const int b = bh >> 4, h = bh & 15;
    #pragma unroll
    for (int mt = 0; mt < 2; ++mt) {
        #pragma unroll
        for (int r = 0; r < 4; ++r) {
            float inv = 1.0f / lacc[mt][r];
            int s = qblk * 128 + w * 32 + mt * 16 + quad * 4 + r;
            size_t rowb = (size_t)(b * Sq + s) * 2048 + br * 1024 + h * 64;
            #pragma unroll
            for (int dt = 0; dt < 4; ++dt)
                ocat[rowb + dt * 16 + ln] = f2bf(oacc[mt][dt][r] * inv);
        }
    }
}

// ---------------------------------------------------------------------------
// Fused output: out = ocat[4096][2048] @ Wfull_bt^T + bfull   (fp32 out)
// ---------------------------------------------------------------------------
__global__ __launch_bounds__(256, 4)
void out_mfma(const u16* __restrict__ ocat, const u16* __restrict__ Wfull_bt,
              const float* __restrict__ bfull, float* __restrict__ outb)
{
    __shared__ u16 As[64 * 64], Bs[128 * 64];
    const int aRow0 = blockIdx.y * 64, nCol0 = blockIdx.x * 128;
    f32x4 acc[2][4] = {};
    gemm_tile_64(ocat, Wfull_bt, 2048, aRow0, nCol0, As, Bs, acc);

    const int tid = threadIdx.x, w = tid >> 6, lane = tid & 63;
    const int ln = lane & 15, quad = lane >> 4;
    const int wm = (w >> 1) * 32, wn = (w & 1) * 64;
    #pragma unroll
    for (int mt = 0; mt < 2; ++mt) {
        #pragma unroll
        for (int nt = 0; nt < 4; ++nt) {
            int gn = nCol0 + wn + nt * 16 + ln;
            float bv = bfull[gn];
            #pragma unroll
            for (int r = 0; r < 4; ++r) {
                int gm = aRow0 + wm + mt * 16 + quad * 4 + r;
                outb[(size_t)gm * 1024 + gn] = acc[mt][nt][r] + bv;
            }
        }
    }
}

// ---------------------------------------------------------------------------
extern "C" void kernel_launch(void* const* d_in, const int* in_sizes, int n_in,
                              void* d_out, int out_size, void* d_ws, size_t ws_size,
                              hipStream_t stream)
{
    const float* x    = (const float*)d_in[0];
    const int*   lidx = (const int*)  d_in[1];
    const float* lamp = (const float*)d_in[2];
    const float* Wq1  = (const float*)d_in[3];
    const float* Wk1  = (const float*)d_in[4];
    const float* Wv1  = (const float*)d_in[5];
    const float* Wo1  = (const float*)d_in[6];
    const float* bq1  = (const float*)d_in[7];
    const float* bk1  = (const float*)d_in[8];
    const float* bv1  = (const float*)d_in[9];
    const float* bo1  = (const float*)d_in[10];
    const float* Wq2  = (const float*)d_in[11];
    const float* Wk2  = (const float*)d_in[12];
    const float* Wv2  = (const float*)d_in[13];
    const float* Wo2  = (const float*)d_in[14];
    const float* bq2  = (const float*)d_in[15];
    const float* bk2  = (const float*)d_in[16];
    const float* bv2  = (const float*)d_in[17];
    const float* bo2  = (const float*)d_in[18];
    const float* Wp   = (const float*)d_in[19];
    const float* bp   = (const float*)d_in[20];

    char* wsb = (char*)d_ws;
    const size_t MB = 1 << 20;
    u16* xb    = (u16*)(wsb + 0 * MB);          // 8 MB
    u16* Wt0   = (u16*)(wsb + 8 * MB);          // 6 x 2 MB
    u16* Wpt   = (u16*)(wsb + 20 * MB);         // 2 MB
    u16* Acat  = (u16*)(wsb + 22 * MB);         // 2112x1024 bf16 = 4.125 MB
    u16* Wfull = (u16*)(wsb + 27 * MB);         // [1024][2048] bf16 = 4 MB
    float* bfull = (float*)(wsb + 31 * MB);     // 4 KB
    u16* qb1   = (u16*)(wsb + 32 * MB);         // 8 MB each
    u16* kb1   = (u16*)(wsb + 40 * MB);
    u16* vb1   = (u16*)(wsb + 48 * MB);
    u16* qb2   = (u16*)(wsb + 56 * MB);
    u16* kb2   = (u16*)(wsb + 64 * MB);
    u16* vb2   = (u16*)(wsb + 72 * MB);
    u16* ocat  = (u16*)(wsb + 80 * MB);         // 16 MB

    convert_x<<<dim3(NT * Dm / 1024), dim3(256), 0, stream>>>(x, xb);

    TcP tp;
    const float* wsrc[7] = {Wq1, Wk1, Wv1, Wq2, Wk2, Wv2, Wp};
    for (int i = 0; i < 7; ++i) tp.src[i] = wsrc[i];
    for (int i = 0; i < 6; ++i) tp.dst[i] = Wt0 + (size_t)i * 1024 * 1024;
    tp.dst[6] = Wpt;
    wconv<<<dim3(16, 16, 7), dim3(256), 0, stream>>>(tp);

    // Acat: [Wo1; -lam*Wo2; bcmb] -> 2049 rows of 1024 (rows 2049..2111 unused)
    woconv<<<dim3(2049), dim3(256), 0, stream>>>(
        Wo1, Wo2, bo1, bo2, lidx, lamp, Acat);

    wfull_mfma<<<dim3(8, 33), dim3(256), 0, stream>>>(
        Acat, Wpt, bp, Wfull, bfull);

    QkvP qp;
    qp.Wt[0] = Wt0 + 0 * 1048576; qp.bias[0] = bq1; qp.out[0] = qb1;
    qp.Wt[1] = Wt0 + 1 * 1048576; qp.bias[1] = bk1; qp.out[1] = kb1;
    qp.Wt[2] = Wt0 + 2 * 1048576; qp.bias[2] = bv1; qp.out[2] = vb1;
    qp.Wt[3] = Wt0 + 3 * 1048576; qp.bias[3] = bq2; qp.out[3] = qb2;
    qp.Wt[4] = Wt0 + 4 * 1048576; qp.bias[4] = bk2; qp.out[4] = kb2;
    qp.Wt[5] = Wt0 + 5 * 1048576; qp.bias[5] = bv2; qp.out[5] = vb2;
    qkv_mfma<<<dim3(8, 32, 6), dim3(256), 0, stream>>>(xb, qp);

    attn_mfma<<<dim3(32, 16, 2), dim3(256), 0, stream>>>(
        qb1, kb1, vb1, qb2, kb2, vb2, ocat);

    out_mfma<<<dim3(8, 64), dim3(256), 0, stream>>>(
        ocat, Wfull, bfull, (float*)d_out);
}